// Round 1
// baseline (1243.200 us; speedup 1.0000x reference)
//
#include <hip/hip_runtime.h>
#include <math.h>

// Problem constants (fixed by the reference)
#define NN 50000          // nodes
#define NE 800000         // edges
#define NE2 (NE + NN)     // edges + self loops = 850000
#define INC 64            // in channels
#define EDD 16            // edge dim
#define NH 4              // heads
#define CC 64             // per-head channels
#define HC 256            // H*C
#define NG 2048           // graphs
#define SLOPE 0.2f

// ---------------- mean edge attr ----------------
__global__ void ea_sum_kernel(const float* __restrict__ ea, float* __restrict__ meansum) {
  __shared__ float part[16];
  if (threadIdx.x < 16) part[threadIdx.x] = 0.f;
  __syncthreads();
  size_t stride = (size_t)gridDim.x * blockDim.x;          // multiple of 16
  size_t i = (size_t)blockIdx.x * blockDim.x + threadIdx.x;
  int cls = (int)(i & 15);                                  // constant along loop
  float s = 0.f;
  const size_t total = (size_t)NE * EDD;
  for (; i < total; i += stride) s += ea[i];
  atomicAdd(&part[cls], s);
  __syncthreads();
  if (threadIdx.x < 16) atomicAdd(&meansum[threadIdx.x], part[threadIdx.x]);
}

__global__ void ea_div_kernel(const float* __restrict__ meansum, float* __restrict__ meanea) {
  if (threadIdx.x < 16) meanea[threadIdx.x] = meansum[threadIdx.x] * (1.0f / NE);
}

// ---------------- CSR build (group edges by dst) ----------------
__global__ void count_dst_kernel(const int* __restrict__ ei, int* __restrict__ counts) {
  int e = blockIdx.x * blockDim.x + threadIdx.x;
  if (e >= NE2) return;
  int d = (e < NE) ? ei[NE + e] : (e - NE);
  atomicAdd(&counts[d], 1);
}

// single-block exclusive scan over N=50000 counts -> row_ptr[0..N]
__global__ void scan_kernel(const int* __restrict__ counts, int* __restrict__ row_ptr) {
  __shared__ int buf[1024];
  __shared__ int carry;
  if (threadIdx.x == 0) carry = 0;
  __syncthreads();
  for (int base = 0; base < NN; base += 1024) {
    int i = base + threadIdx.x;
    int v = (i < NN) ? counts[i] : 0;
    buf[threadIdx.x] = v;
    __syncthreads();
    for (int off = 1; off < 1024; off <<= 1) {
      int t = (threadIdx.x >= off) ? buf[threadIdx.x - off] : 0;
      __syncthreads();
      buf[threadIdx.x] += t;
      __syncthreads();
    }
    int incl = buf[threadIdx.x];
    int total = buf[1023];
    if (i < NN) row_ptr[i] = carry + incl - v;   // exclusive
    __syncthreads();
    if (threadIdx.x == 0) carry += total;
    __syncthreads();
  }
  if (threadIdx.x == 0) row_ptr[NN] = carry;
}

__global__ void fill_kernel(const int* __restrict__ ei, const int* __restrict__ row_ptr,
                            int* __restrict__ cursor, int* __restrict__ eid,
                            int* __restrict__ esrc) {
  int e = blockIdx.x * blockDim.x + threadIdx.x;
  if (e >= NE2) return;
  int d, s;
  if (e < NE) { d = ei[NE + e]; s = ei[e]; }
  else        { d = e - NE;     s = d;     }
  int pos = row_ptr[d] + atomicAdd(&cursor[d], 1);
  eid[pos]  = e;
  esrc[pos] = s;
}

// ---------------- f32 GEMM: Y[n,256] = X[n,K] @ W[K,256] ----------------
// BM=64, BN=64, BK=16, 256 threads, 4x4 per-thread tile.
__global__ __launch_bounds__(256) void gemm256_kernel(const float* __restrict__ X,
                                                      const float* __restrict__ W,
                                                      float* __restrict__ Y,
                                                      int n, int K) {
  __shared__ float Xs[16][64];
  __shared__ float Ws[16][64];
  const int tid = threadIdx.x;
  const int row0 = blockIdx.x * 64;
  const int col0 = blockIdx.y * 64;
  const int tr = tid >> 4, tc = tid & 15;
  float acc[4][4] = {};
  for (int k0 = 0; k0 < K; k0 += 16) {
    // stage X tile (transposed to [k][m])
    {
      int m = tid >> 2, kq = tid & 3;
      float4 v = make_float4(0.f, 0.f, 0.f, 0.f);
      int r = row0 + m;
      if (r < n) v = *(const float4*)(X + (size_t)r * K + k0 + kq * 4);
      Xs[kq * 4 + 0][m] = v.x; Xs[kq * 4 + 1][m] = v.y;
      Xs[kq * 4 + 2][m] = v.z; Xs[kq * 4 + 3][m] = v.w;
    }
    // stage W tile
    {
      int kk = tid >> 4, nq = tid & 15;
      float4 v = *(const float4*)(W + (size_t)(k0 + kk) * HC + col0 + nq * 4);
      Ws[kk][nq * 4 + 0] = v.x; Ws[kk][nq * 4 + 1] = v.y;
      Ws[kk][nq * 4 + 2] = v.z; Ws[kk][nq * 4 + 3] = v.w;
    }
    __syncthreads();
#pragma unroll
    for (int k = 0; k < 16; ++k) {
      float4 a = *(const float4*)(&Xs[k][tr * 4]);
      float4 b = *(const float4*)(&Ws[k][tc * 4]);
      acc[0][0] += a.x * b.x; acc[0][1] += a.x * b.y; acc[0][2] += a.x * b.z; acc[0][3] += a.x * b.w;
      acc[1][0] += a.y * b.x; acc[1][1] += a.y * b.y; acc[1][2] += a.y * b.z; acc[1][3] += a.y * b.w;
      acc[2][0] += a.z * b.x; acc[2][1] += a.z * b.y; acc[2][2] += a.z * b.z; acc[2][3] += a.z * b.w;
      acc[3][0] += a.w * b.x; acc[3][1] += a.w * b.y; acc[3][2] += a.w * b.z; acc[3][3] += a.w * b.w;
    }
    __syncthreads();
  }
#pragma unroll
  for (int i = 0; i < 4; ++i) {
    int r = row0 + tr * 4 + i;
    if (r < n)
      *(float4*)(Y + (size_t)r * HC + col0 + tc * 4) =
          make_float4(acc[i][0], acc[i][1], acc[i][2], acc[i][3]);
  }
}

// ---------------- fused edge score + online softmax + aggregate ----------------
// one wave per dst node; lane owns channels 4*lane..4*lane+3 (head = lane>>4)
__global__ __launch_bounds__(256) void edge_agg_kernel(
    const float* __restrict__ xl, const float* __restrict__ xr,
    const int* __restrict__ row_ptr, const int* __restrict__ eid,
    const int* __restrict__ esrc,
    const float* __restrict__ ea, const float* __restrict__ meanea,
    const float* __restrict__ We, const float* __restrict__ att,
    const float* __restrict__ bias, float* __restrict__ out) {
  int lane = threadIdx.x & 63;
  int node = blockIdx.x * (blockDim.x >> 6) + (threadIdx.x >> 6);
  if (node >= NN) return;
  int col0 = lane * 4;
  // this lane's 4 columns of We (16x4 values) live in registers
  float wrf[16][4];
#pragma unroll
  for (int d = 0; d < 16; ++d) {
    float4 v = *(const float4*)(We + d * HC + col0);
    wrf[d][0] = v.x; wrf[d][1] = v.y; wrf[d][2] = v.z; wrf[d][3] = v.w;
  }
  int h = lane >> 4;
  float4 attv = *(const float4*)(att + h * CC + (lane & 15) * 4);
  float4 xrv = *(const float4*)(xr + (size_t)node * HC + col0);
  float m = -INFINITY, den = 0.f;
  float acc0 = 0.f, acc1 = 0.f, acc2 = 0.f, acc3 = 0.f;
  int beg = row_ptr[node], end = row_ptr[node + 1];
  for (int j = beg; j < end; ++j) {
    int e = eid[j];
    int s = esrc[j];
    const float* eap = (e < NE) ? (ea + (size_t)e * EDD) : meanea;
    float4 xlv = *(const float4*)(xl + (size_t)s * HC + col0);
    float eav[16];
#pragma unroll
    for (int q = 0; q < 4; ++q) {
      float4 v = *(const float4*)(eap + q * 4);
      eav[q * 4 + 0] = v.x; eav[q * 4 + 1] = v.y;
      eav[q * 4 + 2] = v.z; eav[q * 4 + 3] = v.w;
    }
    float ee0 = 0.f, ee1 = 0.f, ee2 = 0.f, ee3 = 0.f;
#pragma unroll
    for (int d = 0; d < 16; ++d) {
      ee0 += eav[d] * wrf[d][0];
      ee1 += eav[d] * wrf[d][1];
      ee2 += eav[d] * wrf[d][2];
      ee3 += eav[d] * wrf[d][3];
    }
    float e0 = xlv.x + xrv.x + ee0;
    float e1 = xlv.y + xrv.y + ee1;
    float e2 = xlv.z + xrv.z + ee2;
    float e3 = xlv.w + xrv.w + ee3;
    e0 = (e0 > 0.f) ? e0 : SLOPE * e0;
    e1 = (e1 > 0.f) ? e1 : SLOPE * e1;
    e2 = (e2 > 0.f) ? e2 : SLOPE * e2;
    e3 = (e3 > 0.f) ? e3 : SLOPE * e3;
    float p = e0 * attv.x + e1 * attv.y + e2 * attv.z + e3 * attv.w;
    p += __shfl_xor(p, 1, 16);
    p += __shfl_xor(p, 2, 16);
    p += __shfl_xor(p, 4, 16);
    p += __shfl_xor(p, 8, 16);
    // online softmax update (per head; uniform within 16-lane group)
    float mn = fmaxf(m, p);
    float sc = __expf(m - mn);   // exp(-inf)=0 handles first edge
    float w  = __expf(p - mn);
    den = den * sc + w;
    acc0 = acc0 * sc + w * xlv.x;
    acc1 = acc1 * sc + w * xlv.y;
    acc2 = acc2 * sc + w * xlv.z;
    acc3 = acc3 * sc + w * xlv.w;
    m = mn;
  }
  float inv = 1.f / (den + 1e-16f);
  float4 bv = *(const float4*)(bias + col0);
  float o0 = fmaxf(acc0 * inv + bv.x, 0.f);
  float o1 = fmaxf(acc1 * inv + bv.y, 0.f);
  float o2 = fmaxf(acc2 * inv + bv.z, 0.f);
  float o3 = fmaxf(acc3 * inv + bv.w, 0.f);
  *(float4*)(out + (size_t)node * HC + col0) = make_float4(o0, o1, o2, o3);
}

// ---------------- global mean pool ----------------
__global__ void pool_kernel(const float* __restrict__ h2, const int* __restrict__ batch,
                            float* __restrict__ pooled, float* __restrict__ pcount) {
  int t = blockIdx.x * blockDim.x + threadIdx.x;
  int node = t >> 6;
  if (node >= NN) return;
  int c0 = (t & 63) * 4;
  int g = batch[node];
  float4 v = *(const float4*)(h2 + (size_t)node * HC + c0);
  atomicAdd(&pooled[(size_t)g * HC + c0 + 0], v.x);
  atomicAdd(&pooled[(size_t)g * HC + c0 + 1], v.y);
  atomicAdd(&pooled[(size_t)g * HC + c0 + 2], v.z);
  atomicAdd(&pooled[(size_t)g * HC + c0 + 3], v.w);
  if ((t & 63) == 0) atomicAdd(&pcount[g], 1.f);
}

// ---------------- final linear: out[g] = mean_pooled . Wf + bf ----------------
__global__ void final_kernel(const float* __restrict__ pooled, const float* __restrict__ pcount,
                             const float* __restrict__ Wf, const float* __restrict__ bf,
                             float* __restrict__ out) {
  int lane = threadIdx.x & 63;
  int g = blockIdx.x * (blockDim.x >> 6) + (threadIdx.x >> 6);
  if (g >= NG) return;
  float4 p = *(const float4*)(pooled + (size_t)g * HC + lane * 4);
  float4 w = *(const float4*)(Wf + lane * 4);
  float s = p.x * w.x + p.y * w.y + p.z * w.z + p.w * w.w;
  s += __shfl_xor(s, 1, 64);  s += __shfl_xor(s, 2, 64);
  s += __shfl_xor(s, 4, 64);  s += __shfl_xor(s, 8, 64);
  s += __shfl_xor(s, 16, 64); s += __shfl_xor(s, 32, 64);
  if (lane == 0) out[g] = s / fmaxf(pcount[g], 1.f) + bf[0];
}

extern "C" void kernel_launch(void* const* d_in, const int* in_sizes, int n_in,
                              void* d_out, int out_size, void* d_ws, size_t ws_size,
                              hipStream_t stream) {
  const float* x    = (const float*)d_in[0];
  const int*   ei   = (const int*)d_in[1];   // [2,E]: src row 0, dst row 1
  const int*   batch= (const int*)d_in[2];
  const float* ea   = (const float*)d_in[3];
  const float* Wl1  = (const float*)d_in[4];
  const float* Wr1  = (const float*)d_in[5];
  const float* We1  = (const float*)d_in[6];
  const float* att1 = (const float*)d_in[7];
  const float* b1   = (const float*)d_in[8];
  const float* Wl2  = (const float*)d_in[9];
  const float* Wr2  = (const float*)d_in[10];
  const float* We2  = (const float*)d_in[11];
  const float* att2 = (const float*)d_in[12];
  const float* b2   = (const float*)d_in[13];
  const float* Wf   = (const float*)d_in[14];
  const float* bf   = (const float*)d_in[15];
  float* out = (float*)d_out;

  // workspace layout (floats then ints); h2 aliases h1 (safe: layer-2 GEMMs
  // finish reading h1 before edge_agg L2 writes it, in-order stream)
  float* xl      = (float*)d_ws;               // N*256
  float* xr      = xl + (size_t)NN * HC;       // N*256
  float* h1      = xr + (size_t)NN * HC;       // N*256
  float* pooled  = h1 + (size_t)NN * HC;       // G*256
  float* pcount  = pooled + (size_t)NG * HC;   // G
  float* meansum = pcount + NG;                // 16
  float* meanea  = meansum + 16;               // 16
  int* counts  = (int*)(meanea + 16);          // N
  int* row_ptr = counts + NN;                  // N+1
  int* eid     = row_ptr + NN + 1;             // E2
  int* esrc    = eid + NE2;                    // E2

  hipMemsetAsync(counts, 0, NN * sizeof(int), stream);
  hipMemsetAsync(meansum, 0, 16 * sizeof(float), stream);
  hipMemsetAsync(pooled, 0, ((size_t)NG * HC + NG) * sizeof(float), stream);

  ea_sum_kernel<<<1024, 256, 0, stream>>>(ea, meansum);
  ea_div_kernel<<<1, 16, 0, stream>>>(meansum, meanea);

  count_dst_kernel<<<(NE2 + 255) / 256, 256, 0, stream>>>(ei, counts);
  scan_kernel<<<1, 1024, 0, stream>>>(counts, row_ptr);
  hipMemsetAsync(counts, 0, NN * sizeof(int), stream);
  fill_kernel<<<(NE2 + 255) / 256, 256, 0, stream>>>(ei, row_ptr, counts, eid, esrc);

  dim3 ggrid((NN + 63) / 64, 4);
  // layer 1
  gemm256_kernel<<<ggrid, 256, 0, stream>>>(x, Wl1, xl, NN, INC);
  gemm256_kernel<<<ggrid, 256, 0, stream>>>(x, Wr1, xr, NN, INC);
  edge_agg_kernel<<<NN / 4, 256, 0, stream>>>(xl, xr, row_ptr, eid, esrc, ea, meanea,
                                              We1, att1, b1, h1);
  // layer 2 (reuse xl/xr buffers)
  gemm256_kernel<<<ggrid, 256, 0, stream>>>(h1, Wl2, xl, NN, HC);
  gemm256_kernel<<<ggrid, 256, 0, stream>>>(h1, Wr2, xr, NN, HC);
  edge_agg_kernel<<<NN / 4, 256, 0, stream>>>(xl, xr, row_ptr, eid, esrc, ea, meanea,
                                              We2, att2, b2, h1);
  // pooling + ffn
  pool_kernel<<<(NN * 64 + 255) / 256, 256, 0, stream>>>(h1, batch, pooled, pcount);
  final_kernel<<<NG / 4, 256, 0, stream>>>(pooled, pcount, Wf, bf, out);
}

// Round 2
// 1050.649 us; speedup vs baseline: 1.1833x; 1.1833x over previous
//
#include <hip/hip_runtime.h>
#include <math.h>

// Problem constants (fixed by the reference)
#define NN 50000          // nodes
#define NE 800000         // edges
#define NE2 (NE + NN)     // edges + self loops = 850000
#define INC 64            // in channels
#define EDD 16            // edge dim
#define NH 4              // heads
#define CC 64             // per-head channels
#define HC 256            // H*C
#define NG 2048           // graphs
#define SLOPE 0.2f

#define RFL(x) __builtin_amdgcn_readfirstlane(x)

// ---------------- mean edge attr ----------------
__global__ void ea_sum_kernel(const float* __restrict__ ea, float* __restrict__ meansum) {
  __shared__ float part[16];
  if (threadIdx.x < 16) part[threadIdx.x] = 0.f;
  __syncthreads();
  size_t stride = (size_t)gridDim.x * blockDim.x;          // multiple of 16
  size_t i = (size_t)blockIdx.x * blockDim.x + threadIdx.x;
  int cls = (int)(i & 15);                                  // constant along loop
  float s = 0.f;
  const size_t total = (size_t)NE * EDD;
  for (; i < total; i += stride) s += ea[i];
  atomicAdd(&part[cls], s);
  __syncthreads();
  if (threadIdx.x < 16) atomicAdd(&meansum[threadIdx.x], part[threadIdx.x]);
}

__global__ void ea_div_kernel(const float* __restrict__ meansum, float* __restrict__ meanea) {
  if (threadIdx.x < 16) meanea[threadIdx.x] = meansum[threadIdx.x] * (1.0f / NE);
}

// ---------------- CSR build (group edges by dst) ----------------
__global__ void count_dst_kernel(const int* __restrict__ ei, int* __restrict__ counts) {
  int e = blockIdx.x * blockDim.x + threadIdx.x;
  if (e >= NE2) return;
  int d = (e < NE) ? ei[NE + e] : (e - NE);
  atomicAdd(&counts[d], 1);
}

// 3-phase exclusive scan over n counts (n <= 256*256)
__global__ void scan_partial_kernel(const int* __restrict__ counts, int n,
                                    int* __restrict__ excl, int* __restrict__ btot) {
  int b = blockIdx.x;
  int i = b * 256 + threadIdx.x;
  int v = (i < n) ? counts[i] : 0;
  int lane = threadIdx.x & 63;
  int incl = v;
#pragma unroll
  for (int off = 1; off < 64; off <<= 1) {
    int t = __shfl_up(incl, off, 64);
    if (lane >= off) incl += t;
  }
  __shared__ int wtot[4];
  int w = threadIdx.x >> 6;
  if (lane == 63) wtot[w] = incl;
  __syncthreads();
  int woff = 0;
#pragma unroll
  for (int k = 0; k < 4; ++k) woff += (k < w) ? wtot[k] : 0;
  incl += woff;
  if (i < n) excl[i] = incl - v;
  if (threadIdx.x == 255) btot[b] = incl;
}

__global__ void scan_btot_kernel(int* __restrict__ btot, int nb, int* __restrict__ totp) {
  __shared__ int buf[256];
  int v = (threadIdx.x < nb) ? btot[threadIdx.x] : 0;
  buf[threadIdx.x] = v;
  __syncthreads();
  for (int off = 1; off < 256; off <<= 1) {
    int t = (threadIdx.x >= off) ? buf[threadIdx.x - off] : 0;
    __syncthreads();
    buf[threadIdx.x] += t;
    __syncthreads();
  }
  if (threadIdx.x < nb) btot[threadIdx.x] = buf[threadIdx.x] - v;  // exclusive
  if (threadIdx.x == 0) *totp = buf[nb - 1];                       // grand total
}

__global__ void scan_add_kernel(int* __restrict__ excl, int n, const int* __restrict__ btot) {
  int i = blockIdx.x * 256 + threadIdx.x;
  if (i < n) excl[i] += btot[blockIdx.x];
}

__global__ void fill_kernel(const int* __restrict__ ei, const int* __restrict__ row_ptr,
                            int* __restrict__ cursor, int2* __restrict__ edg) {
  int e = blockIdx.x * blockDim.x + threadIdx.x;
  if (e >= NE2) return;
  int d, s;
  if (e < NE) { d = ei[NE + e]; s = ei[e]; }
  else        { d = e - NE;     s = d;     }
  int pos = row_ptr[d] + atomicAdd(&cursor[d], 1);
  edg[pos] = make_int2(e, s);
}

// ---------------- f32 GEMM: Y[n,256] = X[n,K] @ W[K,256] ----------------
// BM=64, BN=128, BK=16, 256 threads, 4x8 per-thread tile.
__global__ __launch_bounds__(256, 4) void gemm_kernel(const float* __restrict__ X,
                                                      const float* __restrict__ W,
                                                      float* __restrict__ Y,
                                                      int n, int K) {
  __shared__ float Xs[16][64];
  __shared__ float Ws[16][128];
  const int tid = threadIdx.x;
  const int row0 = blockIdx.x * 64;
  const int col0 = blockIdx.y * 128;
  const int tr = tid >> 4, tc = tid & 15;
  float acc[4][8] = {};
  for (int k0 = 0; k0 < K; k0 += 16) {
    // stage X tile (transposed to [k][m])
    {
      int m = tid >> 2, kq = tid & 3;
      float4 v = make_float4(0.f, 0.f, 0.f, 0.f);
      int r = row0 + m;
      if (r < n) v = *(const float4*)(X + (size_t)r * K + k0 + kq * 4);
      Xs[kq * 4 + 0][m] = v.x; Xs[kq * 4 + 1][m] = v.y;
      Xs[kq * 4 + 2][m] = v.z; Xs[kq * 4 + 3][m] = v.w;
    }
    // stage W tile
    {
      int kk = tid >> 4, nq = tid & 15;
      float4 v0 = *(const float4*)(W + (size_t)(k0 + kk) * HC + col0 + nq * 8);
      float4 v1 = *(const float4*)(W + (size_t)(k0 + kk) * HC + col0 + nq * 8 + 4);
      *(float4*)(&Ws[kk][nq * 8])     = v0;
      *(float4*)(&Ws[kk][nq * 8 + 4]) = v1;
    }
    __syncthreads();
#pragma unroll
    for (int k = 0; k < 16; ++k) {
      float4 a  = *(const float4*)(&Xs[k][tr * 4]);
      float4 b0 = *(const float4*)(&Ws[k][tc * 8]);
      float4 b1 = *(const float4*)(&Ws[k][tc * 8 + 4]);
      float av[4] = {a.x, a.y, a.z, a.w};
      float bv[8] = {b0.x, b0.y, b0.z, b0.w, b1.x, b1.y, b1.z, b1.w};
#pragma unroll
      for (int i = 0; i < 4; ++i)
#pragma unroll
        for (int jj = 0; jj < 8; ++jj) acc[i][jj] += av[i] * bv[jj];
    }
    __syncthreads();
  }
#pragma unroll
  for (int i = 0; i < 4; ++i) {
    int r = row0 + tr * 4 + i;
    if (r < n) {
      *(float4*)(Y + (size_t)r * HC + col0 + tc * 8) =
          make_float4(acc[i][0], acc[i][1], acc[i][2], acc[i][3]);
      *(float4*)(Y + (size_t)r * HC + col0 + tc * 8 + 4) =
          make_float4(acc[i][4], acc[i][5], acc[i][6], acc[i][7]);
    }
  }
}

// ---------------- fused edge score + online softmax + aggregate ----------------
__device__ __forceinline__ float edge_partial(const float* __restrict__ eap,
                                              const float (&wrf)[16][4],
                                              const float4& xrv, const float4& xlv,
                                              const float4& attv) {
  float ee0 = 0.f, ee1 = 0.f, ee2 = 0.f, ee3 = 0.f;
#pragma unroll
  for (int d = 0; d < 16; ++d) {
    float s = eap[d];                       // scalar (SGPR) load: eap is uniform
    ee0 += s * wrf[d][0];
    ee1 += s * wrf[d][1];
    ee2 += s * wrf[d][2];
    ee3 += s * wrf[d][3];
  }
  float t0 = xlv.x + xrv.x + ee0;
  float t1 = xlv.y + xrv.y + ee1;
  float t2 = xlv.z + xrv.z + ee2;
  float t3 = xlv.w + xrv.w + ee3;
  t0 = fmaxf(t0, 0.f) + SLOPE * fminf(t0, 0.f);
  t1 = fmaxf(t1, 0.f) + SLOPE * fminf(t1, 0.f);
  t2 = fmaxf(t2, 0.f) + SLOPE * fminf(t2, 0.f);
  t3 = fmaxf(t3, 0.f) + SLOPE * fminf(t3, 0.f);
  return t0 * attv.x + t1 * attv.y + t2 * attv.z + t3 * attv.w;
}

// one wave per dst node; lane owns channels 4*lane..4*lane+3 (head = lane>>4)
__global__ __launch_bounds__(256, 3) void edge_agg_kernel(
    const float* __restrict__ xl, const float* __restrict__ xr,
    const int* __restrict__ row_ptr, const int2* __restrict__ edg,
    const float* __restrict__ ea, const float* __restrict__ meanea,
    const float* __restrict__ We, const float* __restrict__ att,
    const float* __restrict__ bias, float* __restrict__ out) {
  const int lane = threadIdx.x & 63;
  const int node = blockIdx.x * 4 + (threadIdx.x >> 6);
  if (node >= NN) return;
  const int col0 = lane * 4;
  // this lane's 4 columns of We (16x4 values) live in registers
  float wrf[16][4];
#pragma unroll
  for (int d = 0; d < 16; ++d) {
    float4 v = *(const float4*)(We + d * HC + col0);
    wrf[d][0] = v.x; wrf[d][1] = v.y; wrf[d][2] = v.z; wrf[d][3] = v.w;
  }
  float4 attv = *(const float4*)(att + (lane >> 4) * CC + (lane & 15) * 4);
  float4 xrv  = *(const float4*)(xr + (size_t)node * HC + col0);
  float m = -INFINITY, den = 0.f;
  float acc0 = 0.f, acc1 = 0.f, acc2 = 0.f, acc3 = 0.f;
  int beg = RFL(row_ptr[node]);
  int end = RFL(row_ptr[node + 1]);
  int j = beg;
  for (; j + 1 < end; j += 2) {
    int2 P0 = edg[j];
    int2 P1 = edg[j + 1];
    int e0 = RFL(P0.x), s0 = RFL(P0.y);
    int e1 = RFL(P1.x), s1 = RFL(P1.y);
    const float* ea0 = (e0 < NE) ? (ea + (size_t)e0 * EDD) : meanea;
    const float* ea1 = (e1 < NE) ? (ea + (size_t)e1 * EDD) : meanea;
    float4 xlv0 = *(const float4*)(xl + (size_t)s0 * HC + col0);
    float4 xlv1 = *(const float4*)(xl + (size_t)s1 * HC + col0);
    float q0 = edge_partial(ea0, wrf, xrv, xlv0, attv);
    float q1 = edge_partial(ea1, wrf, xrv, xlv1, attv);
    q0 += __shfl_xor(q0, 1, 16);
    q1 += __shfl_xor(q1, 1, 16);
    q0 += __shfl_xor(q0, 2, 16);
    q1 += __shfl_xor(q1, 2, 16);
    q0 += __shfl_xor(q0, 4, 16);
    q1 += __shfl_xor(q1, 4, 16);
    q0 += __shfl_xor(q0, 8, 16);
    q1 += __shfl_xor(q1, 8, 16);
    float mn = fmaxf(m, fmaxf(q0, q1));
    float sc = __expf(m - mn);      // exp(-inf)=0 handles first pair
    float w0 = __expf(q0 - mn);
    float w1 = __expf(q1 - mn);
    den  = den * sc + w0 + w1;
    acc0 = acc0 * sc + w0 * xlv0.x + w1 * xlv1.x;
    acc1 = acc1 * sc + w0 * xlv0.y + w1 * xlv1.y;
    acc2 = acc2 * sc + w0 * xlv0.z + w1 * xlv1.z;
    acc3 = acc3 * sc + w0 * xlv0.w + w1 * xlv1.w;
    m = mn;
  }
  if (j < end) {                     // tail edge
    int2 P0 = edg[j];
    int e0 = RFL(P0.x), s0 = RFL(P0.y);
    const float* ea0 = (e0 < NE) ? (ea + (size_t)e0 * EDD) : meanea;
    float4 xlv0 = *(const float4*)(xl + (size_t)s0 * HC + col0);
    float q0 = edge_partial(ea0, wrf, xrv, xlv0, attv);
    q0 += __shfl_xor(q0, 1, 16);
    q0 += __shfl_xor(q0, 2, 16);
    q0 += __shfl_xor(q0, 4, 16);
    q0 += __shfl_xor(q0, 8, 16);
    float mn = fmaxf(m, q0);
    float sc = __expf(m - mn);
    float w0 = __expf(q0 - mn);
    den  = den * sc + w0;
    acc0 = acc0 * sc + w0 * xlv0.x;
    acc1 = acc1 * sc + w0 * xlv0.y;
    acc2 = acc2 * sc + w0 * xlv0.z;
    acc3 = acc3 * sc + w0 * xlv0.w;
  }
  float inv = 1.f / (den + 1e-16f);
  float4 bv = *(const float4*)(bias + col0);
  float o0 = fmaxf(acc0 * inv + bv.x, 0.f);
  float o1 = fmaxf(acc1 * inv + bv.y, 0.f);
  float o2 = fmaxf(acc2 * inv + bv.z, 0.f);
  float o3 = fmaxf(acc3 * inv + bv.w, 0.f);
  *(float4*)(out + (size_t)node * HC + col0) = make_float4(o0, o1, o2, o3);
}

// ---------------- graph ranges from sorted batch ----------------
__global__ void graph_bounds_kernel(const int* __restrict__ batch, int* __restrict__ gstart) {
  int i = blockIdx.x * blockDim.x + threadIdx.x;
  if (i >= NN) return;
  int b = batch[i];
  int prev = (i == 0) ? -1 : batch[i - 1];
  for (int g = prev + 1; g <= b; ++g) gstart[g] = i;
  if (i == NN - 1)
    for (int g = b + 1; g <= NG; ++g) gstart[g] = NN;
}

// ---------------- global mean pool: one wave per graph ----------------
__global__ void pool_kernel(const float* __restrict__ h2, const int* __restrict__ gstart,
                            float* __restrict__ pooled) {
  int lane = threadIdx.x & 63;
  int g = blockIdx.x * 4 + (threadIdx.x >> 6);
  if (g >= NG) return;
  int s = RFL(gstart[g]), e = RFL(gstart[g + 1]);
  float sx = 0.f, sy = 0.f, sz = 0.f, sw = 0.f;
  for (int i = s; i < e; ++i) {
    float4 v = *(const float4*)(h2 + (size_t)i * HC + lane * 4);
    sx += v.x; sy += v.y; sz += v.z; sw += v.w;
  }
  float inv = 1.f / fmaxf((float)(e - s), 1.f);
  *(float4*)(pooled + (size_t)g * HC + lane * 4) =
      make_float4(sx * inv, sy * inv, sz * inv, sw * inv);
}

// ---------------- final linear: out[g] = pooled_mean . Wf + bf ----------------
__global__ void final_kernel(const float* __restrict__ pooled,
                             const float* __restrict__ Wf, const float* __restrict__ bf,
                             float* __restrict__ out) {
  int lane = threadIdx.x & 63;
  int g = blockIdx.x * (blockDim.x >> 6) + (threadIdx.x >> 6);
  if (g >= NG) return;
  float4 p = *(const float4*)(pooled + (size_t)g * HC + lane * 4);
  float4 w = *(const float4*)(Wf + lane * 4);
  float s = p.x * w.x + p.y * w.y + p.z * w.z + p.w * w.w;
  s += __shfl_xor(s, 1, 64);  s += __shfl_xor(s, 2, 64);
  s += __shfl_xor(s, 4, 64);  s += __shfl_xor(s, 8, 64);
  s += __shfl_xor(s, 16, 64); s += __shfl_xor(s, 32, 64);
  if (lane == 0) out[g] = s + bf[0];
}

extern "C" void kernel_launch(void* const* d_in, const int* in_sizes, int n_in,
                              void* d_out, int out_size, void* d_ws, size_t ws_size,
                              hipStream_t stream) {
  const float* x    = (const float*)d_in[0];
  const int*   ei   = (const int*)d_in[1];   // [2,E]: src row 0, dst row 1
  const int*   batch= (const int*)d_in[2];
  const float* ea   = (const float*)d_in[3];
  const float* Wl1  = (const float*)d_in[4];
  const float* Wr1  = (const float*)d_in[5];
  const float* We1  = (const float*)d_in[6];
  const float* att1 = (const float*)d_in[7];
  const float* b1   = (const float*)d_in[8];
  const float* Wl2  = (const float*)d_in[9];
  const float* Wr2  = (const float*)d_in[10];
  const float* We2  = (const float*)d_in[11];
  const float* att2 = (const float*)d_in[12];
  const float* b2   = (const float*)d_in[13];
  const float* Wf   = (const float*)d_in[14];
  const float* bf   = (const float*)d_in[15];
  float* out = (float*)d_out;

  // workspace layout
  float* xl      = (float*)d_ws;               // N*256
  float* xr      = xl + (size_t)NN * HC;       // N*256
  float* h1      = xr + (size_t)NN * HC;       // N*256
  float* pooled  = h1 + (size_t)NN * HC;       // G*256
  float* meansum = pooled + (size_t)NG * HC;   // 16
  float* meanea  = meansum + 16;               // 16
  int* counts  = (int*)(meanea + 16);          // N
  int* row_ptr = counts + NN;                  // N+1
  int* btot    = row_ptr + NN + 1;             // 256
  int* gstart  = btot + 256;                   // G+1
  int2* edg    = (int2*)(gstart + NG + 1);     // E2 (8B aligned: offset even)

  const int NB = (NN + 255) / 256;             // 196 scan blocks

  hipMemsetAsync(counts, 0, NN * sizeof(int), stream);
  hipMemsetAsync(meansum, 0, 16 * sizeof(float), stream);

  ea_sum_kernel<<<1024, 256, 0, stream>>>(ea, meansum);
  ea_div_kernel<<<1, 16, 0, stream>>>(meansum, meanea);

  count_dst_kernel<<<(NE2 + 255) / 256, 256, 0, stream>>>(ei, counts);
  scan_partial_kernel<<<NB, 256, 0, stream>>>(counts, NN, row_ptr, btot);
  scan_btot_kernel<<<1, 256, 0, stream>>>(btot, NB, row_ptr + NN);
  scan_add_kernel<<<NB, 256, 0, stream>>>(row_ptr, NN, btot);
  hipMemsetAsync(counts, 0, NN * sizeof(int), stream);
  fill_kernel<<<(NE2 + 255) / 256, 256, 0, stream>>>(ei, row_ptr, counts, edg);
  graph_bounds_kernel<<<(NN + 255) / 256, 256, 0, stream>>>(batch, gstart);

  dim3 ggrid((NN + 63) / 64, 2);
  // layer 1
  gemm_kernel<<<ggrid, 256, 0, stream>>>(x, Wl1, xl, NN, INC);
  gemm_kernel<<<ggrid, 256, 0, stream>>>(x, Wr1, xr, NN, INC);
  edge_agg_kernel<<<(NN + 3) / 4, 256, 0, stream>>>(xl, xr, row_ptr, edg, ea, meanea,
                                                    We1, att1, b1, h1);
  // layer 2 (reuse xl/xr buffers)
  gemm_kernel<<<ggrid, 256, 0, stream>>>(h1, Wl2, xl, NN, HC);
  gemm_kernel<<<ggrid, 256, 0, stream>>>(h1, Wr2, xr, NN, HC);
  edge_agg_kernel<<<(NN + 3) / 4, 256, 0, stream>>>(xl, xr, row_ptr, edg, ea, meanea,
                                                    We2, att2, b2, h1);
  // pooling + ffn
  pool_kernel<<<(NG + 3) / 4, 256, 0, stream>>>(h1, gstart, pooled);
  final_kernel<<<(NG + 3) / 4, 256, 0, stream>>>(pooled, Wf, bf, out);
}

// Round 3
// 985.876 us; speedup vs baseline: 1.2610x; 1.0657x over previous
//
#include <hip/hip_runtime.h>
#include <math.h>

// Problem constants (fixed by the reference)
#define NN 50000          // nodes
#define NE 800000         // edges
#define NE2 (NE + NN)     // edges + self loops = 850000
#define INC 64            // in channels
#define EDD 16            // edge dim
#define NH 4              // heads
#define CC 64             // per-head channels
#define HC 256            // H*C
#define NG 2048           // graphs
#define SLOPE 0.2f

typedef float v2f __attribute__((ext_vector_type(2)));
typedef float v4f __attribute__((ext_vector_type(4)));

#define RFL(x) __builtin_amdgcn_readfirstlane(x)

// ---------------- mean edge attr ----------------
__global__ void ea_sum_kernel(const float* __restrict__ ea, float* __restrict__ meansum) {
  __shared__ float part[16];
  if (threadIdx.x < 16) part[threadIdx.x] = 0.f;
  __syncthreads();
  size_t stride = (size_t)gridDim.x * blockDim.x;          // multiple of 16
  size_t i = (size_t)blockIdx.x * blockDim.x + threadIdx.x;
  int cls = (int)(i & 15);                                  // constant along loop
  float s = 0.f;
  const size_t total = (size_t)NE * EDD;
  for (; i < total; i += stride) s += ea[i];
  atomicAdd(&part[cls], s);
  __syncthreads();
  if (threadIdx.x < 16) atomicAdd(&meansum[threadIdx.x], part[threadIdx.x]);
}

// meanea[d] = meansum[d]/NE ; meanee[c] = sum_d meanea[d]*We[d][c]  (one block, 256 thr)
__global__ void meanee_kernel(const float* __restrict__ meansum,
                              const float* __restrict__ We1, const float* __restrict__ We2,
                              float* __restrict__ meanee1, float* __restrict__ meanee2) {
  int c = threadIdx.x;
  float s1 = 0.f, s2 = 0.f;
#pragma unroll
  for (int d = 0; d < 16; ++d) {
    float m = meansum[d] * (1.0f / NE);
    s1 += m * We1[d * HC + c];
    s2 += m * We2[d * HC + c];
  }
  meanee1[c] = s1;
  meanee2[c] = s2;
}

// ---------------- CSR build (group edges by dst) ----------------
__global__ void count_dst_kernel(const int* __restrict__ ei, int* __restrict__ counts) {
  int e = blockIdx.x * blockDim.x + threadIdx.x;
  if (e >= NE2) return;
  int d = (e < NE) ? ei[NE + e] : (e - NE);
  atomicAdd(&counts[d], 1);
}

// 3-phase exclusive scan over n counts (n <= 256*256)
__global__ void scan_partial_kernel(const int* __restrict__ counts, int n,
                                    int* __restrict__ excl, int* __restrict__ btot) {
  int b = blockIdx.x;
  int i = b * 256 + threadIdx.x;
  int v = (i < n) ? counts[i] : 0;
  int lane = threadIdx.x & 63;
  int incl = v;
#pragma unroll
  for (int off = 1; off < 64; off <<= 1) {
    int t = __shfl_up(incl, off, 64);
    if (lane >= off) incl += t;
  }
  __shared__ int wtot[4];
  int w = threadIdx.x >> 6;
  if (lane == 63) wtot[w] = incl;
  __syncthreads();
  int woff = 0;
#pragma unroll
  for (int k = 0; k < 4; ++k) woff += (k < w) ? wtot[k] : 0;
  incl += woff;
  if (i < n) excl[i] = incl - v;
  if (threadIdx.x == 255) btot[b] = incl;
}

__global__ void scan_btot_kernel(int* __restrict__ btot, int nb, int* __restrict__ totp) {
  __shared__ int buf[256];
  int v = (threadIdx.x < nb) ? btot[threadIdx.x] : 0;
  buf[threadIdx.x] = v;
  __syncthreads();
  for (int off = 1; off < 256; off <<= 1) {
    int t = (threadIdx.x >= off) ? buf[threadIdx.x - off] : 0;
    __syncthreads();
    buf[threadIdx.x] += t;
    __syncthreads();
  }
  if (threadIdx.x < nb) btot[threadIdx.x] = buf[threadIdx.x] - v;  // exclusive
  if (threadIdx.x == 0) *totp = buf[nb - 1];                       // grand total
}

__global__ void scan_add_kernel(int* __restrict__ excl, int n, const int* __restrict__ btot) {
  int i = blockIdx.x * 256 + threadIdx.x;
  if (i < n) excl[i] += btot[blockIdx.x];
}

__global__ void fill_kernel(const int* __restrict__ ei, const int* __restrict__ row_ptr,
                            int* __restrict__ cursor, int2* __restrict__ edg) {
  int e = blockIdx.x * blockDim.x + threadIdx.x;
  if (e >= NE2) return;
  int d, s;
  if (e < NE) { d = ei[NE + e]; s = ei[e]; }
  else        { d = e - NE;     s = d;     }
  int pos = row_ptr[d] + atomicAdd(&cursor[d], 1);
  edg[pos] = make_int2(e, s);
}

// ---------------- f32 GEMM: Y[n,256] = X[n,K] @ W[K,256] ----------------
// BM=64, BN=128, BK=16, 256 threads, 4x8 per-thread tile.
__global__ __launch_bounds__(256, 4) void gemm_kernel(const float* __restrict__ X,
                                                      const float* __restrict__ W,
                                                      float* __restrict__ Y,
                                                      int n, int K) {
  __shared__ float Xs[16][64];
  __shared__ float Ws[16][128];
  const int tid = threadIdx.x;
  const int row0 = blockIdx.x * 64;
  const int col0 = blockIdx.y * 128;
  const int tr = tid >> 4, tc = tid & 15;
  float acc[4][8] = {};
  for (int k0 = 0; k0 < K; k0 += 16) {
    // stage X tile (transposed to [k][m])
    {
      int m = tid >> 2, kq = tid & 3;
      float4 v = make_float4(0.f, 0.f, 0.f, 0.f);
      int r = row0 + m;
      if (r < n) v = *(const float4*)(X + (size_t)r * K + k0 + kq * 4);
      Xs[kq * 4 + 0][m] = v.x; Xs[kq * 4 + 1][m] = v.y;
      Xs[kq * 4 + 2][m] = v.z; Xs[kq * 4 + 3][m] = v.w;
    }
    // stage W tile
    {
      int kk = tid >> 4, nq = tid & 15;
      float4 v0 = *(const float4*)(W + (size_t)(k0 + kk) * HC + col0 + nq * 8);
      float4 v1 = *(const float4*)(W + (size_t)(k0 + kk) * HC + col0 + nq * 8 + 4);
      *(float4*)(&Ws[kk][nq * 8])     = v0;
      *(float4*)(&Ws[kk][nq * 8 + 4]) = v1;
    }
    __syncthreads();
#pragma unroll
    for (int k = 0; k < 16; ++k) {
      float4 a  = *(const float4*)(&Xs[k][tr * 4]);
      float4 b0 = *(const float4*)(&Ws[k][tc * 8]);
      float4 b1 = *(const float4*)(&Ws[k][tc * 8 + 4]);
      float av[4] = {a.x, a.y, a.z, a.w};
      float bv[8] = {b0.x, b0.y, b0.z, b0.w, b1.x, b1.y, b1.z, b1.w};
#pragma unroll
      for (int i = 0; i < 4; ++i)
#pragma unroll
        for (int jj = 0; jj < 8; ++jj) acc[i][jj] += av[i] * bv[jj];
    }
    __syncthreads();
  }
#pragma unroll
  for (int i = 0; i < 4; ++i) {
    int r = row0 + tr * 4 + i;
    if (r < n) {
      *(float4*)(Y + (size_t)r * HC + col0 + tc * 8) =
          make_float4(acc[i][0], acc[i][1], acc[i][2], acc[i][3]);
      *(float4*)(Y + (size_t)r * HC + col0 + tc * 8 + 4) =
          make_float4(acc[i][4], acc[i][5], acc[i][6], acc[i][7]);
    }
  }
}

// ---------------- fused edge score + online softmax + aggregate ----------------
__device__ __forceinline__ v2f lrelu2(v2f t) {
  v2f z = {0.f, 0.f};
  return __builtin_elementwise_max(t, z) + SLOPE * __builtin_elementwise_min(t, z);
}

// ee = ea_row @ We restricted to this lane's 4 columns (packed as 2x v2f)
__device__ __forceinline__ void ee_dot(const float* __restrict__ eap,
                                       const v2f (&w01)[16], const v2f (&w23)[16],
                                       v2f& o01, v2f& o23) {
  v2f a = {0.f, 0.f}, b = {0.f, 0.f};
#pragma unroll
  for (int q = 0; q < 4; ++q) {
    v4f v = __builtin_nontemporal_load((const v4f*)(eap + q * 4));
    a += v.x * w01[q * 4 + 0]; b += v.x * w23[q * 4 + 0];
    a += v.y * w01[q * 4 + 1]; b += v.y * w23[q * 4 + 1];
    a += v.z * w01[q * 4 + 2]; b += v.z * w23[q * 4 + 2];
    a += v.w * w01[q * 4 + 3]; b += v.w * w23[q * 4 + 3];
  }
  o01 = a; o23 = b;
}

// one wave per dst node; lane owns channels 4*lane..4*lane+3 (head = lane>>4)
__global__ __launch_bounds__(256, 3) void edge_agg_kernel(
    const float* __restrict__ xl, const float* __restrict__ xr,
    const int* __restrict__ row_ptr, const int2* __restrict__ edg,
    const float* __restrict__ ea, const float* __restrict__ meanee,
    const float* __restrict__ We, const float* __restrict__ att,
    const float* __restrict__ bias, float* __restrict__ out) {
  const int lane = threadIdx.x & 63;
  const int node = blockIdx.x * 4 + (threadIdx.x >> 6);
  if (node >= NN) return;
  const int col0 = lane * 4;
  // this lane's 4 columns of We (16x4 values) live in registers, packed
  v2f w01[16], w23[16];
#pragma unroll
  for (int d = 0; d < 16; ++d) {
    v4f v = *(const v4f*)(We + d * HC + col0);
    w01[d] = (v2f){v.x, v.y};
    w23[d] = (v2f){v.z, v.w};
  }
  v4f av = *(const v4f*)(att + (lane >> 4) * CC + (lane & 15) * 4);
  v2f att01 = {av.x, av.y}, att23 = {av.z, av.w};
  v4f xv = __builtin_nontemporal_load((const v4f*)(xr + (size_t)node * HC + col0));
  v2f xr01 = {xv.x, xv.y}, xr23 = {xv.z, xv.w};
  v4f sv = *(const v4f*)(meanee + col0);     // self-loop ee (precomputed)
  v2f se01 = {sv.x, sv.y}, se23 = {sv.z, sv.w};

  float m = -INFINITY, den = 0.f;
  v2f acc01 = {0.f, 0.f}, acc23 = {0.f, 0.f};
  const int beg = row_ptr[node];
  const int end = row_ptr[node + 1];

  for (int base = beg; base < end; base += 64) {
    int rem = end - base;
    int cnt = rem < 64 ? rem : 64;
    // wave-preload up to 64 edges (one coalesced load), broadcast via shfl
    int pe = 0, ps = 0;
    if (lane < cnt) { int2 P = edg[base + lane]; pe = P.x; ps = P.y; }
    int j = 0;
    for (; j + 1 < cnt; j += 2) {
      int e0 = __shfl(pe, j, 64),     s0 = __shfl(ps, j, 64);
      int e1 = __shfl(pe, j + 1, 64), s1 = __shfl(ps, j + 1, 64);
      v4f x0 = *(const v4f*)(xl + (size_t)s0 * HC + col0);
      v4f x1 = *(const v4f*)(xl + (size_t)s1 * HC + col0);
      v2f e0a, e0b, e1a, e1b;
      if (e0 < NE) ee_dot(ea + (size_t)e0 * EDD, w01, w23, e0a, e0b);
      else         { e0a = se01; e0b = se23; }
      if (e1 < NE) ee_dot(ea + (size_t)e1 * EDD, w01, w23, e1a, e1b);
      else         { e1a = se01; e1b = se23; }
      v2f x0a = {x0.x, x0.y}, x0b = {x0.z, x0.w};
      v2f x1a = {x1.x, x1.y}, x1b = {x1.z, x1.w};
      v2f p0 = lrelu2(x0a + xr01 + e0a) * att01 + lrelu2(x0b + xr23 + e0b) * att23;
      v2f p1 = lrelu2(x1a + xr01 + e1a) * att01 + lrelu2(x1b + xr23 + e1b) * att23;
      float q0 = p0.x + p0.y;
      float q1 = p1.x + p1.y;
      q0 += __shfl_xor(q0, 1, 16);  q1 += __shfl_xor(q1, 1, 16);
      q0 += __shfl_xor(q0, 2, 16);  q1 += __shfl_xor(q1, 2, 16);
      q0 += __shfl_xor(q0, 4, 16);  q1 += __shfl_xor(q1, 4, 16);
      q0 += __shfl_xor(q0, 8, 16);  q1 += __shfl_xor(q1, 8, 16);
      float mn = fmaxf(m, fmaxf(q0, q1));
      float sc = __expf(m - mn);       // exp(-inf)=0 handles first pair
      float w0 = __expf(q0 - mn);
      float w1 = __expf(q1 - mn);
      den   = den * sc + w0 + w1;
      acc01 = acc01 * sc + w0 * x0a + w1 * x1a;
      acc23 = acc23 * sc + w0 * x0b + w1 * x1b;
      m = mn;
    }
    if (j < cnt) {                     // tail edge
      int e0 = __shfl(pe, j, 64), s0 = __shfl(ps, j, 64);
      v4f x0 = *(const v4f*)(xl + (size_t)s0 * HC + col0);
      v2f e0a, e0b;
      if (e0 < NE) ee_dot(ea + (size_t)e0 * EDD, w01, w23, e0a, e0b);
      else         { e0a = se01; e0b = se23; }
      v2f x0a = {x0.x, x0.y}, x0b = {x0.z, x0.w};
      v2f p0 = lrelu2(x0a + xr01 + e0a) * att01 + lrelu2(x0b + xr23 + e0b) * att23;
      float q0 = p0.x + p0.y;
      q0 += __shfl_xor(q0, 1, 16);
      q0 += __shfl_xor(q0, 2, 16);
      q0 += __shfl_xor(q0, 4, 16);
      q0 += __shfl_xor(q0, 8, 16);
      float mn = fmaxf(m, q0);
      float sc = __expf(m - mn);
      float w0 = __expf(q0 - mn);
      den   = den * sc + w0;
      acc01 = acc01 * sc + w0 * x0a;
      acc23 = acc23 * sc + w0 * x0b;
      m = mn;
    }
  }
  float inv = 1.f / (den + 1e-16f);
  v4f bv = *(const v4f*)(bias + col0);
  v2f o01 = acc01 * inv + (v2f){bv.x, bv.y};
  v2f o23 = acc23 * inv + (v2f){bv.z, bv.w};
  v2f z = {0.f, 0.f};
  o01 = __builtin_elementwise_max(o01, z);   // fused ReLU
  o23 = __builtin_elementwise_max(o23, z);
  v4f o = {o01.x, o01.y, o23.x, o23.y};
  __builtin_nontemporal_store(o, (v4f*)(out + (size_t)node * HC + col0));
}

// ---------------- graph ranges from sorted batch ----------------
__global__ void graph_bounds_kernel(const int* __restrict__ batch, int* __restrict__ gstart) {
  int i = blockIdx.x * blockDim.x + threadIdx.x;
  if (i >= NN) return;
  int b = batch[i];
  int prev = (i == 0) ? -1 : batch[i - 1];
  for (int g = prev + 1; g <= b; ++g) gstart[g] = i;
  if (i == NN - 1)
    for (int g = b + 1; g <= NG; ++g) gstart[g] = NN;
}

// ---------------- global mean pool: one wave per graph ----------------
__global__ void pool_kernel(const float* __restrict__ h2, const int* __restrict__ gstart,
                            float* __restrict__ pooled) {
  int lane = threadIdx.x & 63;
  int g = blockIdx.x * 4 + (threadIdx.x >> 6);
  if (g >= NG) return;
  int s = RFL(gstart[g]), e = RFL(gstart[g + 1]);
  float sx = 0.f, sy = 0.f, sz = 0.f, sw = 0.f;
  for (int i = s; i < e; ++i) {
    float4 v = *(const float4*)(h2 + (size_t)i * HC + lane * 4);
    sx += v.x; sy += v.y; sz += v.z; sw += v.w;
  }
  float inv = 1.f / fmaxf((float)(e - s), 1.f);
  *(float4*)(pooled + (size_t)g * HC + lane * 4) =
      make_float4(sx * inv, sy * inv, sz * inv, sw * inv);
}

// ---------------- final linear: out[g] = pooled_mean . Wf + bf ----------------
__global__ void final_kernel(const float* __restrict__ pooled,
                             const float* __restrict__ Wf, const float* __restrict__ bf,
                             float* __restrict__ out) {
  int lane = threadIdx.x & 63;
  int g = blockIdx.x * (blockDim.x >> 6) + (threadIdx.x >> 6);
  if (g >= NG) return;
  float4 p = *(const float4*)(pooled + (size_t)g * HC + lane * 4);
  float4 w = *(const float4*)(Wf + lane * 4);
  float s = p.x * w.x + p.y * w.y + p.z * w.z + p.w * w.w;
  s += __shfl_xor(s, 1, 64);  s += __shfl_xor(s, 2, 64);
  s += __shfl_xor(s, 4, 64);  s += __shfl_xor(s, 8, 64);
  s += __shfl_xor(s, 16, 64); s += __shfl_xor(s, 32, 64);
  if (lane == 0) out[g] = s + bf[0];
}

extern "C" void kernel_launch(void* const* d_in, const int* in_sizes, int n_in,
                              void* d_out, int out_size, void* d_ws, size_t ws_size,
                              hipStream_t stream) {
  const float* x    = (const float*)d_in[0];
  const int*   ei   = (const int*)d_in[1];   // [2,E]: src row 0, dst row 1
  const int*   batch= (const int*)d_in[2];
  const float* ea   = (const float*)d_in[3];
  const float* Wl1  = (const float*)d_in[4];
  const float* Wr1  = (const float*)d_in[5];
  const float* We1  = (const float*)d_in[6];
  const float* att1 = (const float*)d_in[7];
  const float* b1   = (const float*)d_in[8];
  const float* Wl2  = (const float*)d_in[9];
  const float* Wr2  = (const float*)d_in[10];
  const float* We2  = (const float*)d_in[11];
  const float* att2 = (const float*)d_in[12];
  const float* b2   = (const float*)d_in[13];
  const float* Wf   = (const float*)d_in[14];
  const float* bf   = (const float*)d_in[15];
  float* out = (float*)d_out;

  // workspace layout
  float* xl      = (float*)d_ws;               // N*256
  float* xr      = xl + (size_t)NN * HC;       // N*256
  float* h1      = xr + (size_t)NN * HC;       // N*256
  float* pooled  = h1 + (size_t)NN * HC;       // G*256
  float* meansum = pooled + (size_t)NG * HC;   // 16
  float* meanee1 = meansum + 16;               // 256
  float* meanee2 = meanee1 + 256;              // 256
  int* counts  = (int*)(meanee2 + 256);        // N
  int* row_ptr = counts + NN;                  // N+1
  int* btot    = row_ptr + NN + 1;             // 256
  int* gstart  = btot + 256;                   // G+1
  int2* edg    = (int2*)(gstart + NG + 1);     // E2 (8B aligned: offset even)

  const int NB = (NN + 255) / 256;             // 196 scan blocks

  hipMemsetAsync(counts, 0, NN * sizeof(int), stream);
  hipMemsetAsync(meansum, 0, 16 * sizeof(float), stream);

  ea_sum_kernel<<<1024, 256, 0, stream>>>(ea, meansum);
  meanee_kernel<<<1, 256, 0, stream>>>(meansum, We1, We2, meanee1, meanee2);

  count_dst_kernel<<<(NE2 + 255) / 256, 256, 0, stream>>>(ei, counts);
  scan_partial_kernel<<<NB, 256, 0, stream>>>(counts, NN, row_ptr, btot);
  scan_btot_kernel<<<1, 256, 0, stream>>>(btot, NB, row_ptr + NN);
  scan_add_kernel<<<NB, 256, 0, stream>>>(row_ptr, NN, btot);
  hipMemsetAsync(counts, 0, NN * sizeof(int), stream);
  fill_kernel<<<(NE2 + 255) / 256, 256, 0, stream>>>(ei, row_ptr, counts, edg);
  graph_bounds_kernel<<<(NN + 255) / 256, 256, 0, stream>>>(batch, gstart);

  dim3 ggrid((NN + 63) / 64, 2);
  // layer 1
  gemm_kernel<<<ggrid, 256, 0, stream>>>(x, Wl1, xl, NN, INC);
  gemm_kernel<<<ggrid, 256, 0, stream>>>(x, Wr1, xr, NN, INC);
  edge_agg_kernel<<<(NN + 3) / 4, 256, 0, stream>>>(xl, xr, row_ptr, edg, ea, meanee1,
                                                    We1, att1, b1, h1);
  // layer 2 (reuse xl/xr buffers)
  gemm_kernel<<<ggrid, 256, 0, stream>>>(h1, Wl2, xl, NN, HC);
  gemm_kernel<<<ggrid, 256, 0, stream>>>(h1, Wr2, xr, NN, HC);
  edge_agg_kernel<<<(NN + 3) / 4, 256, 0, stream>>>(xl, xr, row_ptr, edg, ea, meanee2,
                                                    We2, att2, b2, h1);
  // pooling + ffn
  pool_kernel<<<(NG + 3) / 4, 256, 0, stream>>>(h1, gstart, pooled);
  final_kernel<<<(NG + 3) / 4, 256, 0, stream>>>(pooled, Wf, bf, out);
}